// Round 9
// baseline (3591.522 us; speedup 1.0000x reference)
//
#include <hip/hip_runtime.h>
#include <math.h>

typedef __bf16 bf16x8 __attribute__((ext_vector_type(8)));
typedef _Float16 h8 __attribute__((ext_vector_type(8)));
typedef _Float16 h2 __attribute__((ext_vector_type(2)));
typedef float f32x4 __attribute__((ext_vector_type(4)));
typedef float f32x8 __attribute__((ext_vector_type(8)));

__device__ __forceinline__ float clampf(float x, float lo, float hi) {
    return fminf(fmaxf(x, lo), hi);
}

__global__ void zero_ints(int* __restrict__ p, int n) {
    int i = blockIdx.x * 256 + threadIdx.x;
    if (i < n) p[i] = 0;
}

// bf16 B-frag repack for layer 0 only (old layout, CIN=4):
// Wb[((t*KSTEPS + s)*64 + l)*8 + j] = W[k = s*32 + (l>>4)*8 + j][co = t*16 + (l&15)]
__global__ void repack_wb0(const float* __restrict__ cw, unsigned short* __restrict__ Wb) {
    int idx = blockIdx.x * 256 + threadIdx.x;  // total 2*8*512 = 8192
    if (idx >= 8192) return;
    int j = idx & 7;
    int l = (idx >> 3) & 63;
    int rest = idx >> 9;
    int s = rest % 8;
    int t = rest / 8;
    int k = s * 32 + (l >> 4) * 8 + j;  // < 256
    int co = t * 16 + (l & 15);
    float v = cw[k * 32 + co];
    __bf16 h = (__bf16)v;
    Wb[idx] = __builtin_bit_cast(unsigned short, h);
}

// fp16 B-frag repack for CIN=64 layers, permuted k' layout:
// k' < 4096: rowi = k'>>9; ivd = (k'>>7)&3; c = (k'>>1)&63; slot = k'&1;
//            iv = ivd*2+slot; orig_k = (rowi*8+iv)*64 + c  -> cw
// k' >= 4096: fw row (k'-4096)
__global__ void repack_wh(const float* __restrict__ cw, const float* __restrict__ fw,
                          _Float16* __restrict__ Wh, int COUT, int COTILES) {
    int idx = blockIdx.x * 256 + threadIdx.x;
    int total = COTILES * 130 * 512;
    if (idx >= total) return;
    int j = idx & 7;
    int l = (idx >> 3) & 63;
    int rest = idx >> 9;
    int s = rest % 130;
    int t = rest / 130;
    int kp = s * 32 + (l >> 4) * 8 + j;
    int co = t * 16 + (l & 15);
    float v = 0.f;
    if (co < COUT) {
        if (kp < 4096) {
            int rowi = kp >> 9;
            int ivd = (kp >> 7) & 3;
            int c = (kp >> 1) & 63;
            int slot = kp & 1;
            int iv = ivd * 2 + slot;
            v = cw[((rowi * 8 + iv) * 64 + c) * COUT + co];
        } else {
            v = fw[(kp - 4096) * COUT + co];
        }
    }
    Wh[idx] = (_Float16)v;
}

__global__ void edge_hist(const int* __restrict__ ei, const int* __restrict__ ej,
                          int* __restrict__ counts, int E) {
    int e = blockIdx.x * 256 + threadIdx.x;
    if (e >= E) return;
    int i = ei[e], j = ej[e];
    if (i != j) atomicAdd(&counts[i], 1);
}

__global__ __launch_bounds__(1024) void scan_kernel(const int* __restrict__ counts,
                                                    int* __restrict__ offs,
                                                    int* __restrict__ cursor, int N) {
    __shared__ int sums[1024];
    const int t = threadIdx.x;
    const int per = (N + 1023) / 1024;
    const int lo = t * per;
    const int hi = min(lo + per, N);
    int s = 0;
    for (int i = lo; i < hi; ++i) s += counts[i];
    sums[t] = s;
    __syncthreads();
    for (int d = 1; d < 1024; d <<= 1) {
        int v = (t >= d) ? sums[t - d] : 0;
        __syncthreads();
        sums[t] += v;
        __syncthreads();
    }
    int run = (t > 0) ? sums[t - 1] : 0;
    for (int i = lo; i < hi; ++i) {
        offs[i] = run;
        cursor[i] = run;
        run += counts[i];
    }
    if (t == 1023) offs[N] = sums[1023];
}

// csr_jk pack: j[0:17) | rowi0>>1 [17:19) | rowi1>>1 [19:21) | iv [21:24)
// csr_w4[e] = (wu0*gv, wu0*fv, wu1*gv, wu1*fv)
//   wu0 = weight of even tap-row rowi0, wu1 = weight of odd tap-row rowi1
__global__ void edge_scatter(const int* __restrict__ ei, const int* __restrict__ ej,
                             const float* __restrict__ pos, int* __restrict__ cursor,
                             int* __restrict__ csr_jk, float4* __restrict__ csr_w4, int E) {
    int e = blockIdx.x * 256 + threadIdx.x;
    if (e >= E) return;
    int i = ei[e], j = ej[e];
    if (i == j) return;
    float dx = clampf(pos[i * 2 + 0] - pos[j * 2 + 0], -1.f, 1.f);
    float dy = clampf(pos[i * 2 + 1] - pos[j * 2 + 1], -1.f, 1.f);
    float r = sqrtf(dx * dx + dy * dy + 1e-12f);
    float u = clampf(2.f * r - 1.f, -1.f, 1.f);
    float v = atan2f(dy, dx) * 0.3183098861837907f;  // / pi
    float tu = (u + 1.f) * 3.5f;
    float tv = (v + 1.f) * 3.5f;
    int iu = min(6, max(0, (int)floorf(tu)));
    int iv = min(6, max(0, (int)floorf(tv)));
    float fu = clampf(tu - (float)iu, 0.f, 1.f);
    float fv = clampf(tv - (float)iv, 0.f, 1.f);
    bool even = (iu & 1) == 0;
    int rowi0 = even ? iu : iu + 1;      // even row
    int rowi1 = even ? iu + 1 : iu;      // odd row
    float wu0 = even ? (1.f - fu) : fu;
    float wu1 = even ? fu : (1.f - fu);
    float gv = 1.f - fv;
    int p = atomicAdd(&cursor[i], 1);
    csr_jk[p] = j | ((rowi0 >> 1) << 17) | ((rowi1 >> 1) << 19) | (iv << 21);
    csr_w4[p] = make_float4(wu0 * gv, wu0 * fv, wu1 * gv, wu1 * fv);
}

__device__ __forceinline__ bf16x8 frag_from_lds_f32(const float* arow, int s, int quad) {
    const float4* ap = (const float4*)(arow + s * 32 + quad * 8);
    float4 a0 = ap[0], a1 = ap[1];
    f32x8 av = {a0.x, a0.y, a0.z, a0.w, a1.x, a1.y, a1.z, a1.w};
    return __builtin_convertvector(av, bf16x8);
}

// ---------------------------------------------------------------------------
// Layers 1..3 (CIN=64). 1024 threads = 16 waves, TM=8 nodes, fp16 moments.
// Moment layout (halfs, per node row of RS=4168): bins k' = rowi*512 + ivd*128
// + c*2 + slot (iv = ivd*2+slot), dense row at k' = 4096+c. The iv/iv+1 tap
// pair of one visit is one aligned half2 (even iv) or two (odd iv) ->
// v_pk_add_f16 RMW, banks = c mod 32 (conflict-free). 2 parity waves per node
// (p=0 even tap-rows, p=1 odd) -> race-free, no ds atomics. 66.7 KB LDS ->
// 2 blocks/CU: scatter and GEMM phases of neighbor blocks overlap.
// GEMM: 16-way K-split, A-frags are direct fp16 (no convert), f16 MFMA.
// MODE 1: relu in, out = conv(+dense row) + cb + fb
// MODE 2: MODE1 + residual x ;  MODE 3: COUT=2, /128
template <int MODE>
__global__ __launch_bounds__(1024, 8) void conv64_mfma(
    const float* __restrict__ x, const _Float16* __restrict__ Wh,
    const float* __restrict__ cb, const float* __restrict__ fb,
    const int* __restrict__ offs, const int* __restrict__ csr_jk,
    const float4* __restrict__ csr_w4, float* __restrict__ out, int nNodes) {
    constexpr int TM = 8;
    constexpr int KSTEPS = 130;
    constexpr int RSH = 4168;       // halfs per node row (pad 8 halfs)
    constexpr int RSD = RSH / 2;    // 2084 dwords
    extern __shared__ float mom[];  // 8 * 4168 * 2 B = 66688 B
    const int tid = threadIdx.x;
    const int w = tid >> 6;
    const int lane = tid & 63;
    const int node = w >> 1;
    const int p = w & 1;
    const int base = blockIdx.x * TM;
    const int n = base + node;

    {  // zero moments (66688 B = 4168 float4)
        float4 z = make_float4(0.f, 0.f, 0.f, 0.f);
        float4* m4 = (float4*)mom;
        for (int i = tid; i < TM * RSH / 8; i += 1024) m4[i] = z;
    }
    __syncthreads();

    // ---- scatter
    if (n < nNodes) {
        const int e0 = offs[n], e1 = offs[n + 1];
        h2* momn2 = (h2*)mom + node * RSD;
        const int c = lane;
        const float2* w2p = (const float2*)csr_w4;
        for (int b = e0; b < e1; b += 4) {
            int jk[4];
            float2 w2[4];
            float xv[4];
#pragma unroll
            for (int u = 0; u < 4; ++u) {
                int e = b + u;
                bool ok = e < e1;
                int ee = ok ? e : e0;
                jk[u] = csr_jk[ee];
                w2[u] = w2p[2 * ee + p];
                xv[u] = ok ? 1.f : 0.f;
            }
#pragma unroll
            for (int u = 0; u < 4; ++u) {
                int j = jk[u] & 0x1FFFF;
                xv[u] *= fmaxf(x[j * 64 + c], 0.f);
            }
#pragma unroll
            for (int u = 0; u < 4; ++u) {
                int rowi = (((jk[u] >> (17 + 2 * p)) & 3) << 1) + p;
                int iv = (jk[u] >> 21) & 7;
                int ivd = iv >> 1;
                float wa = w2[u].x * xv[u];
                float wb = w2[u].y * xv[u];
                h2* bp = momn2 + rowi * 256 + ivd * 64 + c;
                if ((iv & 1) == 0) {  // wave-uniform branch
                    h2 v = {(_Float16)wa, (_Float16)wb};
                    *bp += v;
                } else {
                    h2 v0 = {(_Float16)0.f, (_Float16)wa};
                    h2 v1 = {(_Float16)wb, (_Float16)0.f};
                    bp[0] += v0;
                    bp[64] += v1;
                }
            }
        }
        if (p == 0) {  // dense row k' = 4096 + lane
            ((_Float16*)mom)[node * RSH + 4096 + lane] =
                (_Float16)fmaxf(x[n * 64 + lane], 0.f);
        }
    }

    // ---- GEMM: K-chunk for this wave (130 = 2*9 + 14*8)
    const int s0 = w * 8 + min(w, 2);
    const int s_end = s0 + 8 + (w < 2 ? 1 : 0);
    const int row = lane & 15;
    const int quad = lane >> 4;
    const _Float16* arow = (const _Float16*)mom + (row & 7) * RSH;

    if (MODE == 3) {
        const uint4* Bp = (const uint4*)Wh;
        // prefetch before barrier (independent of LDS)
        uint4 b0 = Bp[(size_t)(s0 + 0) * 64 + lane];
        uint4 b1 = Bp[(size_t)(s0 + 1) * 64 + lane];
        uint4 b2 = Bp[(size_t)(s0 + 2) * 64 + lane];
        uint4 b3 = Bp[(size_t)(s0 + 3) * 64 + lane];
        __syncthreads();
        f32x4 acc = {0, 0, 0, 0};
        for (int s = s0; s < s_end; ++s) {
            uint4 bq = b0;
            b0 = b1; b1 = b2; b2 = b3;
            if (s + 4 < s_end) b3 = Bp[(size_t)(s + 4) * 64 + lane];
            h8 a = *(const h8*)(arow + s * 32 + quad * 8);
            acc = __builtin_amdgcn_mfma_f32_16x16x32_f16(a, __builtin_bit_cast(h8, bq), acc,
                                                         0, 0, 0);
        }
        __syncthreads();
        f32x4* red = (f32x4*)mom;
        red[w * 64 + lane] = acc;
        __syncthreads();
        if (w == 0) {
            f32x4 s = {0, 0, 0, 0};
#pragma unroll
            for (int g = 0; g < 16; ++g) s += red[g * 64 + lane];
            const int co = lane & 15;
            if (co < 2 && quad < 2) {
#pragma unroll
                for (int i = 0; i < 4; ++i) {
                    int nn = base + quad * 4 + i;
                    if (nn < nNodes) out[nn * 2 + co] = (s[i] + cb[co] + fb[co]) * (1.f / 128.f);
                }
            }
        }
    } else {
        const uint4* Bp = (const uint4*)Wh;
        uint4 b0[4], b1[4];
#pragma unroll
        for (int t = 0; t < 4; ++t) {  // prefetch before barrier
            b0[t] = Bp[((size_t)t * KSTEPS + s0) * 64 + lane];
            b1[t] = Bp[((size_t)t * KSTEPS + s0 + 1) * 64 + lane];
        }
        __syncthreads();
        f32x4 acc[4] = {{0, 0, 0, 0}, {0, 0, 0, 0}, {0, 0, 0, 0}, {0, 0, 0, 0}};
        for (int s = s0; s < s_end; ++s) {
            uint4 bq[4];
#pragma unroll
            for (int t = 0; t < 4; ++t) {
                bq[t] = b0[t];
                b0[t] = b1[t];
                if (s + 2 < s_end) b1[t] = Bp[((size_t)t * KSTEPS + s + 2) * 64 + lane];
            }
            h8 a = *(const h8*)(arow + s * 32 + quad * 8);
#pragma unroll
            for (int t = 0; t < 4; ++t)
                acc[t] = __builtin_amdgcn_mfma_f32_16x16x32_f16(
                    a, __builtin_bit_cast(h8, bq[t]), acc[t], 0, 0, 0);
        }
        __syncthreads();  // moments dead -> reuse as reduce scratch
        f32x4* red = (f32x4*)mom;
#pragma unroll
        for (int t = 0; t < 4; ++t) red[(w * 4 + t) * 64 + lane] = acc[t];
        __syncthreads();
        if (w < 4) {
            f32x4 s = {0, 0, 0, 0};
#pragma unroll
            for (int g = 0; g < 16; ++g) s += red[(g * 4 + w) * 64 + lane];
            if (lane < 32) {
                const int co = w * 16 + (lane & 15);
#pragma unroll
                for (int i = 0; i < 4; ++i) {
                    int nn = base + quad * 4 + i;
                    if (nn < nNodes) {
                        float res = s[i] + cb[co] + fb[co];
                        if (MODE == 2) res += x[nn * 64 + co];
                        out[nn * 64 + co] = res;
                    }
                }
            }
        }
    }
}

// ---------------------------------------------------------------------------
// Layer 0 (CIN=4). TM=8. Register-resident bin scatter (lane = 8x8 bin), fp32
// moments, bf16 MFMA (old k-order). 2 edge-half waves/node into 2 LDS copies.
__global__ __launch_bounds__(1024, 4) void conv0_mfma(
    const float* __restrict__ x, const unsigned short* __restrict__ Wb,
    const float* __restrict__ cb, const float* __restrict__ fb, const float* __restrict__ fw,
    const int* __restrict__ offs, const int* __restrict__ csr_jk,
    const float4* __restrict__ csr_w4, float* __restrict__ out, int nNodes) {
    constexpr int TM = 8;
    constexpr int KSTEPS = 8;
    constexpr int RS = 256 + 12;    // 268
    extern __shared__ float mom[];  // [16][RS]
    const int tid = threadIdx.x;
    const int w = tid >> 6;
    const int lane = tid & 63;
    const int node = w >> 1;
    const int h = w & 1;
    const int base = blockIdx.x * TM;
    const int n = base + node;

    {
        float4 z = make_float4(0.f, 0.f, 0.f, 0.f);
        float4* m4 = (float4*)mom;
        for (int i = tid; i < 16 * RS / 4; i += 1024) m4[i] = z;
    }
    __syncthreads();

    if (n < nNodes) {
        const int e0 = offs[n], e1 = offs[n + 1];
        const int len = e1 - e0;
        const int hl = (len + 1) >> 1;
        const int bs = e0 + h * hl;
        const int be = min(bs + hl, e1);
        const int iu_l = lane >> 3, iv_l = lane & 7;
        f32x4 v = {0, 0, 0, 0};
        for (int e = bs; e < be; ++e) {
            int jk = csr_jk[e];
            float4 w4 = csr_w4[e];
            int j = jk & 0x1FFFF;
            int r0 = ((jk >> 17) & 3) << 1;
            int r1 = (((jk >> 19) & 3) << 1) + 1;
            int iv = (jk >> 21) & 7;
            float wgt = 0.f;
            if (iu_l == r0) wgt = (iv_l == iv) ? w4.x : ((iv_l == iv + 1) ? w4.y : 0.f);
            else if (iu_l == r1) wgt = (iv_l == iv) ? w4.z : ((iv_l == iv + 1) ? w4.w : 0.f);
            const float4 xj = *(const float4*)(x + j * 4);
            v.x += wgt * xj.x;
            v.y += wgt * xj.y;
            v.z += wgt * xj.z;
            v.w += wgt * xj.w;
        }
        ((float4*)(mom + (h * 8 + node) * RS))[lane] = *(float4*)&v;
    }
    __syncthreads();

    for (int idx = tid; idx < TM * 64; idx += 1024) {
        int r = idx >> 6, off = idx & 63;
        float4 s0 = ((float4*)(mom + r * RS))[off];
        float4 s1 = ((float4*)(mom + (8 + r) * RS))[off];
        s0.x += s1.x;
        s0.y += s1.y;
        s0.z += s1.z;
        s0.w += s1.w;
        ((float4*)(mom + r * RS))[off] = s0;
    }
    __syncthreads();

    const int row = lane & 15;
    const int quad = lane >> 4;
    const float* arow = mom + (row & 7) * RS;
    if (w < 2) {
        const uint4* Bp = (const uint4*)Wb + (size_t)w * KSTEPS * 64;
        f32x4 acc = {0, 0, 0, 0};
        uint4 b0 = Bp[lane], b1 = Bp[64 + lane], b2 = Bp[128 + lane], b3 = Bp[192 + lane];
        for (int s = 0; s < KSTEPS; ++s) {
            uint4 bq = b0;
            b0 = b1; b1 = b2; b2 = b3;
            if (s + 4 < KSTEPS) b3 = Bp[(size_t)(s + 4) * 64 + lane];
            bf16x8 a = frag_from_lds_f32(arow, s, quad);
            acc = __builtin_amdgcn_mfma_f32_16x16x32_bf16(a, __builtin_bit_cast(bf16x8, bq),
                                                          acc, 0, 0, 0);
        }
        if (lane < 32) {
            const int co = w * 16 + (lane & 15);
#pragma unroll
            for (int i = 0; i < 4; ++i) {
                int nn = base + quad * 4 + i;
                if (nn < nNodes) out[nn * 64 + 32 + co] = acc[i] + cb[co];
            }
        }
    } else if (w >= 2 && w < 6) {
        const int co = lane & 31;
        const int r = (w - 2) * 2 + (lane >> 5);
        int nn = base + r;
        if (nn < nNodes) {
            const float4 xr = *(const float4*)(x + nn * 4);
            float sdot = xr.x * fw[co] + xr.y * fw[32 + co] + xr.z * fw[64 + co] +
                         xr.w * fw[96 + co] + fb[co];
            out[nn * 64 + co] = sdot;
        }
    }
}

extern "C" void kernel_launch(void* const* d_in, const int* in_sizes, int n_in,
                              void* d_out, int out_size, void* d_ws, size_t ws_size,
                              hipStream_t stream) {
    const float* pos = (const float*)d_in[0];
    const float* feat = (const float*)d_in[1];
    const int* ei = (const int*)d_in[2];
    const int* ej = (const int*)d_in[3];
    const float* cw0 = (const float*)d_in[4];
    const float* cb0 = (const float*)d_in[5];
    const float* fw0 = (const float*)d_in[6];
    const float* fb0 = (const float*)d_in[7];
    const float* cw1 = (const float*)d_in[8];
    const float* cb1 = (const float*)d_in[9];
    const float* fw1 = (const float*)d_in[10];
    const float* fb1 = (const float*)d_in[11];
    const float* cw2 = (const float*)d_in[12];
    const float* cb2 = (const float*)d_in[13];
    const float* fw2 = (const float*)d_in[14];
    const float* fb2 = (const float*)d_in[15];
    const float* cw3 = (const float*)d_in[16];
    const float* cb3 = (const float*)d_in[17];
    const float* fw3 = (const float*)d_in[18];
    const float* fb3 = (const float*)d_in[19];
    float* outp = (float*)d_out;

    const int N = in_sizes[0] / 2;
    const int E = in_sizes[2];

    char* wsp = (char*)d_ws;
    size_t off = 0;
    auto alloc = [&](size_t bytes) -> void* {
        void* p = wsp + off;
        off = (off + bytes + 255) & ~(size_t)255;
        return p;
    };
    int* counts = (int*)alloc((size_t)N * 4);
    int* offs = (int*)alloc((size_t)(N + 1) * 4);
    int* cursor = (int*)alloc((size_t)N * 4);
    int* csr_jk = (int*)alloc((size_t)E * 4);
    float4* csr_w4 = (float4*)alloc((size_t)E * 16);
    float* ansA = (float*)alloc((size_t)N * 64 * 4);
    float* ansB = (float*)alloc((size_t)N * 64 * 4);
    unsigned short* Wb0 = (unsigned short*)alloc((size_t)8192 * 2);
    _Float16* Wh1 = (_Float16*)alloc((size_t)4 * 130 * 512 * 2);
    _Float16* Wh2 = (_Float16*)alloc((size_t)4 * 130 * 512 * 2);
    _Float16* Wh3 = (_Float16*)alloc((size_t)1 * 130 * 512 * 2);
    (void)ws_size;
    (void)n_in;
    (void)out_size;

    const int BIG_LDS = 8 * 4168 * 2;              // 66688 B -> 2 blocks/CU
    const int SMALL_LDS = 16 * (256 + 12) * 4;     // 17152 B
    hipFuncSetAttribute((const void*)&conv64_mfma<1>,
                        hipFuncAttributeMaxDynamicSharedMemorySize, BIG_LDS);
    hipFuncSetAttribute((const void*)&conv64_mfma<2>,
                        hipFuncAttributeMaxDynamicSharedMemorySize, BIG_LDS);
    hipFuncSetAttribute((const void*)&conv64_mfma<3>,
                        hipFuncAttributeMaxDynamicSharedMemorySize, BIG_LDS);

    zero_ints<<<dim3((N + 255) / 256), dim3(256), 0, stream>>>(counts, N);
    repack_wb0<<<dim3(32), dim3(256), 0, stream>>>(cw0, Wb0);
    repack_wh<<<dim3((4 * 130 * 512 + 255) / 256), dim3(256), 0, stream>>>(cw1, fw1, Wh1, 64, 4);
    repack_wh<<<dim3((4 * 130 * 512 + 255) / 256), dim3(256), 0, stream>>>(cw2, fw2, Wh2, 64, 4);
    repack_wh<<<dim3((1 * 130 * 512 + 255) / 256), dim3(256), 0, stream>>>(cw3, fw3, Wh3, 2, 1);
    edge_hist<<<dim3((E + 255) / 256), dim3(256), 0, stream>>>(ei, ej, counts, E);
    scan_kernel<<<dim3(1), dim3(1024), 0, stream>>>(counts, offs, cursor, N);
    edge_scatter<<<dim3((E + 255) / 256), dim3(256), 0, stream>>>(ei, ej, pos, cursor, csr_jk,
                                                                  csr_w4, E);

    const int nb = (N + 7) / 8;
    conv0_mfma<<<dim3(nb), dim3(1024), SMALL_LDS, stream>>>(
        feat, Wb0, cb0, fb0, fw0, offs, csr_jk, csr_w4, ansA, N);
    conv64_mfma<1><<<dim3(nb), dim3(1024), BIG_LDS, stream>>>(
        ansA, Wh1, cb1, fb1, offs, csr_jk, csr_w4, ansB, N);
    conv64_mfma<2><<<dim3(nb), dim3(1024), BIG_LDS, stream>>>(
        ansB, Wh2, cb2, fb2, offs, csr_jk, csr_w4, ansA, N);
    conv64_mfma<3><<<dim3(nb), dim3(1024), BIG_LDS, stream>>>(
        ansA, Wh3, cb3, fb3, offs, csr_jk, csr_w4, outp, N);
}

// Round 10
// 1684.342 us; speedup vs baseline: 2.1323x; 2.1323x over previous
//
#include <hip/hip_runtime.h>
#include <math.h>

typedef __bf16 bf16x8 __attribute__((ext_vector_type(8)));
typedef _Float16 h8 __attribute__((ext_vector_type(8)));
typedef _Float16 h2 __attribute__((ext_vector_type(2)));
typedef float f32x4 __attribute__((ext_vector_type(4)));
typedef float f32x8 __attribute__((ext_vector_type(8)));

__device__ __forceinline__ float clampf(float x, float lo, float hi) {
    return fminf(fmaxf(x, lo), hi);
}

__global__ void zero_ints(int* __restrict__ p, int n) {
    int i = blockIdx.x * 256 + threadIdx.x;
    if (i < n) p[i] = 0;
}

// bf16 B-frag repack for layer 0 only (old layout, CIN=4):
// Wb[((t*KSTEPS + s)*64 + l)*8 + j] = W[k = s*32 + (l>>4)*8 + j][co = t*16 + (l&15)]
__global__ void repack_wb0(const float* __restrict__ cw, unsigned short* __restrict__ Wb) {
    int idx = blockIdx.x * 256 + threadIdx.x;  // total 2*8*512 = 8192
    if (idx >= 8192) return;
    int j = idx & 7;
    int l = (idx >> 3) & 63;
    int rest = idx >> 9;
    int s = rest % 8;
    int t = rest / 8;
    int k = s * 32 + (l >> 4) * 8 + j;  // < 256
    int co = t * 16 + (l & 15);
    float v = cw[k * 32 + co];
    __bf16 h = (__bf16)v;
    Wb[idx] = __builtin_bit_cast(unsigned short, h);
}

// fp16 B-frag repack for CIN=64 layers, permuted k' layout:
// k' < 4096: rowi = k'>>9; ivd = (k'>>7)&3; c = (k'>>1)&63; slot = k'&1;
//            iv = ivd*2+slot; orig_k = (rowi*8+iv)*64 + c  -> cw
// k' >= 4096: fw row (k'-4096)
__global__ void repack_wh(const float* __restrict__ cw, const float* __restrict__ fw,
                          _Float16* __restrict__ Wh, int COUT, int COTILES) {
    int idx = blockIdx.x * 256 + threadIdx.x;
    int total = COTILES * 130 * 512;
    if (idx >= total) return;
    int j = idx & 7;
    int l = (idx >> 3) & 63;
    int rest = idx >> 9;
    int s = rest % 130;
    int t = rest / 130;
    int kp = s * 32 + (l >> 4) * 8 + j;
    int co = t * 16 + (l & 15);
    float v = 0.f;
    if (co < COUT) {
        if (kp < 4096) {
            int rowi = kp >> 9;
            int ivd = (kp >> 7) & 3;
            int c = (kp >> 1) & 63;
            int slot = kp & 1;
            int iv = ivd * 2 + slot;
            v = cw[((rowi * 8 + iv) * 64 + c) * COUT + co];
        } else {
            v = fw[(kp - 4096) * COUT + co];
        }
    }
    Wh[idx] = (_Float16)v;
}

__global__ void edge_hist(const int* __restrict__ ei, const int* __restrict__ ej,
                          int* __restrict__ counts, int E) {
    int e = blockIdx.x * 256 + threadIdx.x;
    if (e >= E) return;
    int i = ei[e], j = ej[e];
    if (i != j) atomicAdd(&counts[i], 1);
}

__global__ __launch_bounds__(1024) void scan_kernel(const int* __restrict__ counts,
                                                    int* __restrict__ offs,
                                                    int* __restrict__ cursor, int N) {
    __shared__ int sums[1024];
    const int t = threadIdx.x;
    const int per = (N + 1023) / 1024;
    const int lo = t * per;
    const int hi = min(lo + per, N);
    int s = 0;
    for (int i = lo; i < hi; ++i) s += counts[i];
    sums[t] = s;
    __syncthreads();
    for (int d = 1; d < 1024; d <<= 1) {
        int v = (t >= d) ? sums[t - d] : 0;
        __syncthreads();
        sums[t] += v;
        __syncthreads();
    }
    int run = (t > 0) ? sums[t - 1] : 0;
    for (int i = lo; i < hi; ++i) {
        offs[i] = run;
        cursor[i] = run;
        run += counts[i];
    }
    if (t == 1023) offs[N] = sums[1023];
}

// csr_jk pack: j[0:17) | rowi0>>1 [17:19) | rowi1>>1 [19:21) | iv [21:24)
// csr_w4[e] = (wu0*gv, wu0*fv, wu1*gv, wu1*fv)
//   wu0 = weight of even tap-row rowi0, wu1 = weight of odd tap-row rowi1
__global__ void edge_scatter(const int* __restrict__ ei, const int* __restrict__ ej,
                             const float* __restrict__ pos, int* __restrict__ cursor,
                             int* __restrict__ csr_jk, float4* __restrict__ csr_w4, int E) {
    int e = blockIdx.x * 256 + threadIdx.x;
    if (e >= E) return;
    int i = ei[e], j = ej[e];
    if (i == j) return;
    float dx = clampf(pos[i * 2 + 0] - pos[j * 2 + 0], -1.f, 1.f);
    float dy = clampf(pos[i * 2 + 1] - pos[j * 2 + 1], -1.f, 1.f);
    float r = sqrtf(dx * dx + dy * dy + 1e-12f);
    float u = clampf(2.f * r - 1.f, -1.f, 1.f);
    float v = atan2f(dy, dx) * 0.3183098861837907f;  // / pi
    float tu = (u + 1.f) * 3.5f;
    float tv = (v + 1.f) * 3.5f;
    int iu = min(6, max(0, (int)floorf(tu)));
    int iv = min(6, max(0, (int)floorf(tv)));
    float fu = clampf(tu - (float)iu, 0.f, 1.f);
    float fv = clampf(tv - (float)iv, 0.f, 1.f);
    bool even = (iu & 1) == 0;
    int rowi0 = even ? iu : iu + 1;      // even row
    int rowi1 = even ? iu + 1 : iu;      // odd row
    float wu0 = even ? (1.f - fu) : fu;
    float wu1 = even ? fu : (1.f - fu);
    float gv = 1.f - fv;
    int p = atomicAdd(&cursor[i], 1);
    csr_jk[p] = j | ((rowi0 >> 1) << 17) | ((rowi1 >> 1) << 19) | (iv << 21);
    csr_w4[p] = make_float4(wu0 * gv, wu0 * fv, wu1 * gv, wu1 * fv);
}

__device__ __forceinline__ bf16x8 frag_from_lds_f32(const float* arow, int s, int quad) {
    const float4* ap = (const float4*)(arow + s * 32 + quad * 8);
    float4 a0 = ap[0], a1 = ap[1];
    f32x8 av = {a0.x, a0.y, a0.z, a0.w, a1.x, a1.y, a1.z, a1.w};
    return __builtin_convertvector(av, bf16x8);
}

// ---------------------------------------------------------------------------
// Layers 1..3 (CIN=64). 1024 threads = 16 waves, TM=8 nodes, fp16 moments.
// Moment layout (halfs, per node row of RSH=4168): bins k' = rowi*512 +
// ivd*128 + c*2 + slot (iv = ivd*2+slot), dense row at k' = 4096+c. The
// iv/iv+1 tap pair of one visit is one aligned half2 (even iv) or two (odd)
// -> packed f16 RMW, banks = c mod 32 (conflict-free). 2 parity waves per
// node (p=0 even tap-rows, p=1 odd) -> race-free, no ds atomics (3x slower,
// round 6). 66.7 KB LDS -> 2 blocks/CU when VGPR<=64: neighbor blocks overlap
// scatter and GEMM phases. GEMM: 16-way K-split, direct fp16 A-frags, f16
// MFMA. __launch_bounds__(1024,4): round 9's (1024,8) forced 32 VGPRs ->
// catastrophic scratch spill (2.5 GB writes).
// MODE 1: relu in, out = conv(+dense row) + cb + fb
// MODE 2: MODE1 + residual x ;  MODE 3: COUT=2, /128
template <int MODE>
__global__ __launch_bounds__(1024, 4) void conv64_mfma(
    const float* __restrict__ x, const _Float16* __restrict__ Wh,
    const float* __restrict__ cb, const float* __restrict__ fb,
    const int* __restrict__ offs, const int* __restrict__ csr_jk,
    const float4* __restrict__ csr_w4, float* __restrict__ out, int nNodes) {
    constexpr int TM = 8;
    constexpr int KSTEPS = 130;
    constexpr int RSH = 4168;       // halfs per node row (pad 8 halfs)
    constexpr int RSD = RSH / 2;    // 2084 dwords
    extern __shared__ float mom[];  // 8 * 4168 * 2 B = 66688 B
    const int tid = threadIdx.x;
    const int w = tid >> 6;
    const int lane = tid & 63;
    const int node = w >> 1;
    const int p = w & 1;
    const int base = blockIdx.x * TM;
    const int n = base + node;

    {  // zero moments (66688 B = 4168 float4)
        float4 z = make_float4(0.f, 0.f, 0.f, 0.f);
        float4* m4 = (float4*)mom;
        for (int i = tid; i < TM * RSH / 8; i += 1024) m4[i] = z;
    }
    __syncthreads();

    // ---- scatter
    if (n < nNodes) {
        const int e0 = offs[n], e1 = offs[n + 1];
        h2* momn2 = (h2*)mom + node * RSD;
        const int c = lane;
        const float2* w2p = (const float2*)csr_w4;
        for (int b = e0; b < e1; b += 4) {
            int jk[4];
            float2 w2[4];
            float xv[4];
#pragma unroll
            for (int u = 0; u < 4; ++u) {
                int e = b + u;
                bool ok = e < e1;
                int ee = ok ? e : e0;
                jk[u] = csr_jk[ee];
                w2[u] = w2p[2 * ee + p];
                xv[u] = ok ? 1.f : 0.f;
            }
#pragma unroll
            for (int u = 0; u < 4; ++u) {
                int j = jk[u] & 0x1FFFF;
                xv[u] *= fmaxf(x[j * 64 + c], 0.f);
            }
#pragma unroll
            for (int u = 0; u < 4; ++u) {
                int rowi = (((jk[u] >> (17 + 2 * p)) & 3) << 1) + p;
                int iv = (jk[u] >> 21) & 7;
                int ivd = iv >> 1;
                float wa = w2[u].x * xv[u];
                float wb = w2[u].y * xv[u];
                h2* bp = momn2 + rowi * 256 + ivd * 64 + c;
                if ((iv & 1) == 0) {  // wave-uniform branch
                    h2 v = {(_Float16)wa, (_Float16)wb};
                    *bp += v;
                } else {
                    h2 v0 = {(_Float16)0.f, (_Float16)wa};
                    h2 v1 = {(_Float16)wb, (_Float16)0.f};
                    bp[0] += v0;
                    bp[64] += v1;
                }
            }
        }
        if (p == 0) {  // dense row k' = 4096 + lane
            ((_Float16*)mom)[node * RSH + 4096 + lane] =
                (_Float16)fmaxf(x[n * 64 + lane], 0.f);
        }
    }

    // ---- GEMM: K-chunk for this wave (130 = 2*9 + 14*8)
    const int s0 = w * 8 + min(w, 2);
    const int s_end = s0 + 8 + (w < 2 ? 1 : 0);
    const int row = lane & 15;
    const int quad = lane >> 4;
    const _Float16* arow = (const _Float16*)mom + (row & 7) * RSH;

    if (MODE == 3) {
        const uint4* Bp = (const uint4*)Wh;
        // prefetch before barrier (independent of LDS)
        uint4 b0 = Bp[(size_t)(s0 + 0) * 64 + lane];
        uint4 b1 = Bp[(size_t)(s0 + 1) * 64 + lane];
        uint4 b2 = Bp[(size_t)(s0 + 2) * 64 + lane];
        uint4 b3 = Bp[(size_t)(s0 + 3) * 64 + lane];
        __syncthreads();
        f32x4 acc = {0, 0, 0, 0};
        for (int s = s0; s < s_end; ++s) {
            uint4 bq = b0;
            b0 = b1; b1 = b2; b2 = b3;
            if (s + 4 < s_end) b3 = Bp[(size_t)(s + 4) * 64 + lane];
            h8 a = *(const h8*)(arow + s * 32 + quad * 8);
            acc = __builtin_amdgcn_mfma_f32_16x16x32_f16(a, __builtin_bit_cast(h8, bq), acc,
                                                         0, 0, 0);
        }
        __syncthreads();
        f32x4* red = (f32x4*)mom;
        red[w * 64 + lane] = acc;
        __syncthreads();
        if (w == 0) {
            f32x4 s = {0, 0, 0, 0};
#pragma unroll
            for (int g = 0; g < 16; ++g) s += red[g * 64 + lane];
            const int co = lane & 15;
            if (co < 2 && quad < 2) {
#pragma unroll
                for (int i = 0; i < 4; ++i) {
                    int nn = base + quad * 4 + i;
                    if (nn < nNodes) out[nn * 2 + co] = (s[i] + cb[co] + fb[co]) * (1.f / 128.f);
                }
            }
        }
    } else {
        const uint4* Bp = (const uint4*)Wh;
        uint4 b0[4], b1[4];
#pragma unroll
        for (int t = 0; t < 4; ++t) {  // prefetch before barrier
            b0[t] = Bp[((size_t)t * KSTEPS + s0) * 64 + lane];
            b1[t] = Bp[((size_t)t * KSTEPS + s0 + 1) * 64 + lane];
        }
        __syncthreads();
        f32x4 acc[4] = {{0, 0, 0, 0}, {0, 0, 0, 0}, {0, 0, 0, 0}, {0, 0, 0, 0}};
        for (int s = s0; s < s_end; ++s) {
            uint4 bq[4];
#pragma unroll
            for (int t = 0; t < 4; ++t) {
                bq[t] = b0[t];
                b0[t] = b1[t];
                if (s + 2 < s_end) b1[t] = Bp[((size_t)t * KSTEPS + s + 2) * 64 + lane];
            }
            h8 a = *(const h8*)(arow + s * 32 + quad * 8);
#pragma unroll
            for (int t = 0; t < 4; ++t)
                acc[t] = __builtin_amdgcn_mfma_f32_16x16x32_f16(
                    a, __builtin_bit_cast(h8, bq[t]), acc[t], 0, 0, 0);
        }
        __syncthreads();  // moments dead -> reuse as reduce scratch
        f32x4* red = (f32x4*)mom;
#pragma unroll
        for (int t = 0; t < 4; ++t) red[(w * 4 + t) * 64 + lane] = acc[t];
        __syncthreads();
        if (w < 4) {
            f32x4 s = {0, 0, 0, 0};
#pragma unroll
            for (int g = 0; g < 16; ++g) s += red[(g * 4 + w) * 64 + lane];
            if (lane < 32) {
                const int co = w * 16 + (lane & 15);
#pragma unroll
                for (int i = 0; i < 4; ++i) {
                    int nn = base + quad * 4 + i;
                    if (nn < nNodes) {
                        float res = s[i] + cb[co] + fb[co];
                        if (MODE == 2) res += x[nn * 64 + co];
                        out[nn * 64 + co] = res;
                    }
                }
            }
        }
    }
}

// ---------------------------------------------------------------------------
// Layer 0 (CIN=4). TM=8. Register-resident bin scatter (lane = 8x8 bin), fp32
// moments, bf16 MFMA (old k-order). 2 edge-half waves/node into 2 LDS copies.
__global__ __launch_bounds__(1024, 4) void conv0_mfma(
    const float* __restrict__ x, const unsigned short* __restrict__ Wb,
    const float* __restrict__ cb, const float* __restrict__ fb, const float* __restrict__ fw,
    const int* __restrict__ offs, const int* __restrict__ csr_jk,
    const float4* __restrict__ csr_w4, float* __restrict__ out, int nNodes) {
    constexpr int TM = 8;
    constexpr int KSTEPS = 8;
    constexpr int RS = 256 + 12;    // 268
    extern __shared__ float mom[];  // [16][RS]
    const int tid = threadIdx.x;
    const int w = tid >> 6;
    const int lane = tid & 63;
    const int node = w >> 1;
    const int h = w & 1;
    const int base = blockIdx.x * TM;
    const int n = base + node;

    {
        float4 z = make_float4(0.f, 0.f, 0.f, 0.f);
        float4* m4 = (float4*)mom;
        for (int i = tid; i < 16 * RS / 4; i += 1024) m4[i] = z;
    }
    __syncthreads();

    if (n < nNodes) {
        const int e0 = offs[n], e1 = offs[n + 1];
        const int len = e1 - e0;
        const int hl = (len + 1) >> 1;
        const int bs = e0 + h * hl;
        const int be = min(bs + hl, e1);
        const int iu_l = lane >> 3, iv_l = lane & 7;
        f32x4 v = {0, 0, 0, 0};
        for (int e = bs; e < be; ++e) {
            int jk = csr_jk[e];
            float4 w4 = csr_w4[e];
            int j = jk & 0x1FFFF;
            int r0 = ((jk >> 17) & 3) << 1;
            int r1 = (((jk >> 19) & 3) << 1) + 1;
            int iv = (jk >> 21) & 7;
            float wgt = 0.f;
            if (iu_l == r0) wgt = (iv_l == iv) ? w4.x : ((iv_l == iv + 1) ? w4.y : 0.f);
            else if (iu_l == r1) wgt = (iv_l == iv) ? w4.z : ((iv_l == iv + 1) ? w4.w : 0.f);
            const float4 xj = *(const float4*)(x + j * 4);
            v.x += wgt * xj.x;
            v.y += wgt * xj.y;
            v.z += wgt * xj.z;
            v.w += wgt * xj.w;
        }
        ((float4*)(mom + (h * 8 + node) * RS))[lane] = *(float4*)&v;
    }
    __syncthreads();

    for (int idx = tid; idx < TM * 64; idx += 1024) {
        int r = idx >> 6, off = idx & 63;
        float4 s0 = ((float4*)(mom + r * RS))[off];
        float4 s1 = ((float4*)(mom + (8 + r) * RS))[off];
        s0.x += s1.x;
        s0.y += s1.y;
        s0.z += s1.z;
        s0.w += s1.w;
        ((float4*)(mom + r * RS))[off] = s0;
    }
    __syncthreads();

    const int row = lane & 15;
    const int quad = lane >> 4;
    const float* arow = mom + (row & 7) * RS;
    if (w < 2) {
        const uint4* Bp = (const uint4*)Wb + (size_t)w * KSTEPS * 64;
        f32x4 acc = {0, 0, 0, 0};
        uint4 b0 = Bp[lane], b1 = Bp[64 + lane], b2 = Bp[128 + lane], b3 = Bp[192 + lane];
        for (int s = 0; s < KSTEPS; ++s) {
            uint4 bq = b0;
            b0 = b1; b1 = b2; b2 = b3;
            if (s + 4 < KSTEPS) b3 = Bp[(size_t)(s + 4) * 64 + lane];
            bf16x8 a = frag_from_lds_f32(arow, s, quad);
            acc = __builtin_amdgcn_mfma_f32_16x16x32_bf16(a, __builtin_bit_cast(bf16x8, bq),
                                                          acc, 0, 0, 0);
        }
        if (lane < 32) {
            const int co = w * 16 + (lane & 15);
#pragma unroll
            for (int i = 0; i < 4; ++i) {
                int nn = base + quad * 4 + i;
                if (nn < nNodes) out[nn * 64 + 32 + co] = acc[i] + cb[co];
            }
        }
    } else if (w >= 2 && w < 6) {
        const int co = lane & 31;
        const int r = (w - 2) * 2 + (lane >> 5);
        int nn = base + r;
        if (nn < nNodes) {
            const float4 xr = *(const float4*)(x + nn * 4);
            float sdot = xr.x * fw[co] + xr.y * fw[32 + co] + xr.z * fw[64 + co] +
                         xr.w * fw[96 + co] + fb[co];
            out[nn * 64 + co] = sdot;
        }
    }
}

extern "C" void kernel_launch(void* const* d_in, const int* in_sizes, int n_in,
                              void* d_out, int out_size, void* d_ws, size_t ws_size,
                              hipStream_t stream) {
    const float* pos = (const float*)d_in[0];
    const float* feat = (const float*)d_in[1];
    const int* ei = (const int*)d_in[2];
    const int* ej = (const int*)d_in[3];
    const float* cw0 = (const float*)d_in[4];
    const float* cb0 = (const float*)d_in[5];
    const float* fw0 = (const float*)d_in[6];
    const float* fb0 = (const float*)d_in[7];
    const float* cw1 = (const float*)d_in[8];
    const float* cb1 = (const float*)d_in[9];
    const float* fw1 = (const float*)d_in[10];
    const float* fb1 = (const float*)d_in[11];
    const float* cw2 = (const float*)d_in[12];
    const float* cb2 = (const float*)d_in[13];
    const float* fw2 = (const float*)d_in[14];
    const float* fb2 = (const float*)d_in[15];
    const float* cw3 = (const float*)d_in[16];
    const float* cb3 = (const float*)d_in[17];
    const float* fw3 = (const float*)d_in[18];
    const float* fb3 = (const float*)d_in[19];
    float* outp = (float*)d_out;

    const int N = in_sizes[0] / 2;
    const int E = in_sizes[2];

    char* wsp = (char*)d_ws;
    size_t off = 0;
    auto alloc = [&](size_t bytes) -> void* {
        void* p = wsp + off;
        off = (off + bytes + 255) & ~(size_t)255;
        return p;
    };
    int* counts = (int*)alloc((size_t)N * 4);
    int* offs = (int*)alloc((size_t)(N + 1) * 4);
    int* cursor = (int*)alloc((size_t)N * 4);
    int* csr_jk = (int*)alloc((size_t)E * 4);
    float4* csr_w4 = (float4*)alloc((size_t)E * 16);
    float* ansA = (float*)alloc((size_t)N * 64 * 4);
    float* ansB = (float*)alloc((size_t)N * 64 * 4);
    unsigned short* Wb0 = (unsigned short*)alloc((size_t)8192 * 2);
    _Float16* Wh1 = (_Float16*)alloc((size_t)4 * 130 * 512 * 2);
    _Float16* Wh2 = (_Float16*)alloc((size_t)4 * 130 * 512 * 2);
    _Float16* Wh3 = (_Float16*)alloc((size_t)1 * 130 * 512 * 2);
    (void)ws_size;
    (void)n_in;
    (void)out_size;

    const int BIG_LDS = 8 * 4168 * 2;           // 66688 B -> 2 blocks/CU (VGPR<=64)
    const int SMALL_LDS = 16 * (256 + 12) * 4;  // 17152 B
    hipFuncSetAttribute((const void*)&conv64_mfma<1>,
                        hipFuncAttributeMaxDynamicSharedMemorySize, BIG_LDS);
    hipFuncSetAttribute((const void*)&conv64_mfma<2>,
                        hipFuncAttributeMaxDynamicSharedMemorySize, BIG_LDS);
    hipFuncSetAttribute((const void*)&conv64_mfma<3>,
                        hipFuncAttributeMaxDynamicSharedMemorySize, BIG_LDS);

    zero_ints<<<dim3((N + 255) / 256), dim3(256), 0, stream>>>(counts, N);
    repack_wb0<<<dim3(32), dim3(256), 0, stream>>>(cw0, Wb0);
    repack_wh<<<dim3((4 * 130 * 512 + 255) / 256), dim3(256), 0, stream>>>(cw1, fw1, Wh1, 64, 4);
    repack_wh<<<dim3((4 * 130 * 512 + 255) / 256), dim3(256), 0, stream>>>(cw2, fw2, Wh2, 64, 4);
    repack_wh<<<dim3((1 * 130 * 512 + 255) / 256), dim3(256), 0, stream>>>(cw3, fw3, Wh3, 2, 1);
    edge_hist<<<dim3((E + 255) / 256), dim3(256), 0, stream>>>(ei, ej, counts, E);
    scan_kernel<<<dim3(1), dim3(1024), 0, stream>>>(counts, offs, cursor, N);
    edge_scatter<<<dim3((E + 255) / 256), dim3(256), 0, stream>>>(ei, ej, pos, cursor, csr_jk,
                                                                  csr_w4, E);

    const int nb = (N + 7) / 8;
    conv0_mfma<<<dim3(nb), dim3(1024), SMALL_LDS, stream>>>(
        feat, Wb0, cb0, fb0, fw0, offs, csr_jk, csr_w4, ansA, N);
    conv64_mfma<1><<<dim3(nb), dim3(1024), BIG_LDS, stream>>>(
        ansA, Wh1, cb1, fb1, offs, csr_jk, csr_w4, ansB, N);
    conv64_mfma<2><<<dim3(nb), dim3(1024), BIG_LDS, stream>>>(
        ansB, Wh2, cb2, fb2, offs, csr_jk, csr_w4, ansA, N);
    conv64_mfma<3><<<dim3(nb), dim3(1024), BIG_LDS, stream>>>(
        ansA, Wh3, cb3, fb3, offs, csr_jk, csr_w4, outp, N);
}

// Round 11
// 1487.820 us; speedup vs baseline: 2.4139x; 1.1321x over previous
//
#include <hip/hip_runtime.h>
#include <math.h>

typedef __bf16 bf16x8 __attribute__((ext_vector_type(8)));
typedef _Float16 h8 __attribute__((ext_vector_type(8)));
typedef _Float16 h2 __attribute__((ext_vector_type(2)));
typedef float f32x4 __attribute__((ext_vector_type(4)));
typedef float f32x8 __attribute__((ext_vector_type(8)));

__device__ __forceinline__ float clampf(float x, float lo, float hi) {
    return fminf(fmaxf(x, lo), hi);
}

__global__ void zero_ints(int* __restrict__ p, int n) {
    int i = blockIdx.x * 256 + threadIdx.x;
    if (i < n) p[i] = 0;
}

// bf16 B-frag repack for layer 0 only (old k-order, CIN=4):
// Wb[((t*KSTEPS + s)*64 + l)*8 + j] = W[k = s*32 + (l>>4)*8 + j][co = t*16 + (l&15)]
__global__ void repack_wb0(const float* __restrict__ cw, unsigned short* __restrict__ Wb) {
    int idx = blockIdx.x * 256 + threadIdx.x;  // total 2*8*512 = 8192
    if (idx >= 8192) return;
    int j = idx & 7;
    int l = (idx >> 3) & 63;
    int rest = idx >> 9;
    int s = rest % 8;
    int t = rest / 8;
    int k = s * 32 + (l >> 4) * 8 + j;  // < 256
    int co = t * 16 + (l & 15);
    float v = cw[k * 32 + co];
    __bf16 h = (__bf16)v;
    Wb[idx] = __builtin_bit_cast(unsigned short, h);
}

// fp16 B-frag repack for CIN=64 layers, permuted k' layout:
// k' < 4096: rowi = k'>>9; ivd = (k'>>7)&3; c = (k'>>1)&63; slot = k'&1;
//            iv = ivd*2+slot; orig_k = (rowi*8+iv)*64 + c  -> cw
// k' >= 4096: fw row (k'-4096)
__global__ void repack_wh(const float* __restrict__ cw, const float* __restrict__ fw,
                          _Float16* __restrict__ Wh, int COUT, int COTILES) {
    int idx = blockIdx.x * 256 + threadIdx.x;
    int total = COTILES * 130 * 512;
    if (idx >= total) return;
    int j = idx & 7;
    int l = (idx >> 3) & 63;
    int rest = idx >> 9;
    int s = rest % 130;
    int t = rest / 130;
    int kp = s * 32 + (l >> 4) * 8 + j;
    int co = t * 16 + (l & 15);
    float v = 0.f;
    if (co < COUT) {
        if (kp < 4096) {
            int rowi = kp >> 9;
            int ivd = (kp >> 7) & 3;
            int c = (kp >> 1) & 63;
            int slot = kp & 1;
            int iv = ivd * 2 + slot;
            v = cw[((rowi * 8 + iv) * 64 + c) * COUT + co];
        } else {
            v = fw[(kp - 4096) * COUT + co];
        }
    }
    Wh[idx] = (_Float16)v;
}

__global__ void edge_hist(const int* __restrict__ ei, const int* __restrict__ ej,
                          int* __restrict__ counts, int E) {
    int e = blockIdx.x * 256 + threadIdx.x;
    if (e >= E) return;
    int i = ei[e], j = ej[e];
    if (i != j) atomicAdd(&counts[i], 1);
}

__global__ __launch_bounds__(1024) void scan_kernel(const int* __restrict__ counts,
                                                    int* __restrict__ offs,
                                                    int* __restrict__ cursor, int N) {
    __shared__ int sums[1024];
    const int t = threadIdx.x;
    const int per = (N + 1023) / 1024;
    const int lo = t * per;
    const int hi = min(lo + per, N);
    int s = 0;
    for (int i = lo; i < hi; ++i) s += counts[i];
    sums[t] = s;
    __syncthreads();
    for (int d = 1; d < 1024; d <<= 1) {
        int v = (t >= d) ? sums[t - d] : 0;
        __syncthreads();
        sums[t] += v;
        __syncthreads();
    }
    int run = (t > 0) ? sums[t - 1] : 0;
    for (int i = lo; i < hi; ++i) {
        offs[i] = run;
        cursor[i] = run;
        run += counts[i];
    }
    if (t == 1023) offs[N] = sums[1023];
}

// csr_jk pack: j[0:17) | rowi0>>1 [17:19) | rowi1>>1 [19:21) | iv [21:24)
// csr_w4[e] = fp32 (wu0*gv, wu0*fv, wu1*gv, wu1*fv)  (conv0 path)
// csr_wh[e] = same 4 values as fp16 pairs {lo=*gv, hi=*fv} x {row0,row1} (conv64)
__global__ void edge_scatter(const int* __restrict__ ei, const int* __restrict__ ej,
                             const float* __restrict__ pos, int* __restrict__ cursor,
                             int* __restrict__ csr_jk, float4* __restrict__ csr_w4,
                             uint2* __restrict__ csr_wh, int E) {
    int e = blockIdx.x * 256 + threadIdx.x;
    if (e >= E) return;
    int i = ei[e], j = ej[e];
    if (i == j) return;
    float dx = clampf(pos[i * 2 + 0] - pos[j * 2 + 0], -1.f, 1.f);
    float dy = clampf(pos[i * 2 + 1] - pos[j * 2 + 1], -1.f, 1.f);
    float r = sqrtf(dx * dx + dy * dy + 1e-12f);
    float u = clampf(2.f * r - 1.f, -1.f, 1.f);
    float v = atan2f(dy, dx) * 0.3183098861837907f;  // / pi
    float tu = (u + 1.f) * 3.5f;
    float tv = (v + 1.f) * 3.5f;
    int iu = min(6, max(0, (int)floorf(tu)));
    int iv = min(6, max(0, (int)floorf(tv)));
    float fu = clampf(tu - (float)iu, 0.f, 1.f);
    float fv = clampf(tv - (float)iv, 0.f, 1.f);
    bool even = (iu & 1) == 0;
    int rowi0 = even ? iu : iu + 1;  // even row
    int rowi1 = even ? iu + 1 : iu;  // odd row
    float wu0 = even ? (1.f - fu) : fu;
    float wu1 = even ? fu : (1.f - fu);
    float gv = 1.f - fv;
    int p = atomicAdd(&cursor[i], 1);
    csr_jk[p] = j | ((rowi0 >> 1) << 17) | ((rowi1 >> 1) << 19) | (iv << 21);
    csr_w4[p] = make_float4(wu0 * gv, wu0 * fv, wu1 * gv, wu1 * fv);
    unsigned a0 = (unsigned)__builtin_bit_cast(unsigned short, (_Float16)(wu0 * gv)) |
                  ((unsigned)__builtin_bit_cast(unsigned short, (_Float16)(wu0 * fv)) << 16);
    unsigned a1 = (unsigned)__builtin_bit_cast(unsigned short, (_Float16)(wu1 * gv)) |
                  ((unsigned)__builtin_bit_cast(unsigned short, (_Float16)(wu1 * fv)) << 16);
    csr_wh[p] = make_uint2(a0, a1);
}

__device__ __forceinline__ bf16x8 frag_from_lds_f32(const float* arow, int s, int quad) {
    const float4* ap = (const float4*)(arow + s * 32 + quad * 8);
    float4 a0 = ap[0], a1 = ap[1];
    f32x8 av = {a0.x, a0.y, a0.z, a0.w, a1.x, a1.y, a1.z, a1.w};
    return __builtin_convertvector(av, bf16x8);
}

// ---------------------------------------------------------------------------
// Layers 1..3 (CIN=64). 1024 threads = 16 waves = 16 nodes (TM=16), fp16
// moments, ONE wave per node applying ALL 4 taps (race-free: lane = channel is
// exclusive; same-lane RMWs are program-ordered). Single edge traversal (E
// visits, was 2E with parity waves). Packed-fp16 tap math: 2 v_pk_mul_f16 +
// 2-4 h2 RMWs per edge. Plain RMW (no ds atomics: 3x slower, round 6).
// 133 KB LDS -> 1 block/CU, but all 16 MFMA A-rows useful -> B traffic/FLOP
// halves vs TM=8. GEMM: 16-way K-split, direct fp16 A-frags, f16 MFMA.
// MODE 1: relu in, out = conv(+dense row) + cb + fb
// MODE 2: MODE1 + residual x ;  MODE 3: COUT=2, /128
template <int MODE>
__global__ __launch_bounds__(1024, 4) void conv64_mfma(
    const float* __restrict__ x, const _Float16* __restrict__ Wh,
    const float* __restrict__ cb, const float* __restrict__ fb,
    const int* __restrict__ offs, const int* __restrict__ csr_jk,
    const uint2* __restrict__ csr_wh, float* __restrict__ out, int nNodes) {
    constexpr int TM = 16;
    constexpr int KSTEPS = 130;
    constexpr int RSH = 4168;       // halfs per node row (8336 B)
    constexpr int RSD = RSH / 2;    // 2084 h2 per row
    extern __shared__ float mom[];  // 16 * 8336 B = 133376 B
    const int tid = threadIdx.x;
    const int w = tid >> 6;
    const int lane = tid & 63;
    const int base = blockIdx.x * TM;
    const int n = base + w;

    {  // zero moments: 133376 B = 8336 float4
        float4 z = make_float4(0.f, 0.f, 0.f, 0.f);
        float4* m4 = (float4*)mom;
        for (int i = tid; i < TM * RSH / 8; i += 1024) m4[i] = z;
    }
    __syncthreads();

    // ---- scatter: wave w owns node base+w, all 4 taps, packed fp16 RMW
    if (n < nNodes) {
        const int e0 = offs[n], e1 = offs[n + 1];
        h2* momn2 = (h2*)mom + w * RSD;
        const int c = lane;
        for (int b = e0; b < e1; b += 4) {
            int jk[4];
            uint2 wh[4];
            float xv[4];
#pragma unroll
            for (int u = 0; u < 4; ++u) {
                int e = b + u;
                bool ok = e < e1;
                int ee = ok ? e : e0;
                jk[u] = csr_jk[ee];
                wh[u] = csr_wh[ee];
                xv[u] = ok ? 1.f : 0.f;
            }
#pragma unroll
            for (int u = 0; u < 4; ++u) {
                int j = jk[u] & 0x1FFFF;
                xv[u] *= fmaxf(x[j * 64 + c], 0.f);
            }
#pragma unroll
            for (int u = 0; u < 4; ++u) {
                int r0 = ((jk[u] >> 17) & 3) << 1;
                int r1 = (((jk[u] >> 19) & 3) << 1) + 1;
                int iv = (jk[u] >> 21) & 7;
                int ivd = iv >> 1;
                _Float16 xh = (_Float16)xv[u];
                h2 xh2 = {xh, xh};
                h2 v0 = xh2 * __builtin_bit_cast(h2, wh[u].x);  // {*gv, *fv} row r0
                h2 v1 = xh2 * __builtin_bit_cast(h2, wh[u].y);  // {*gv, *fv} row r1
                h2* bp0 = momn2 + r0 * 256 + ivd * 64 + c;
                h2* bp1 = momn2 + r1 * 256 + ivd * 64 + c;
                if ((iv & 1) == 0) {  // wave-uniform branch (one edge per wave)
                    bp0[0] += v0;
                    bp1[0] += v1;
                } else {  // iv odd: slot 1 of ivd gets *gv, slot 0 of ivd+1 gets *fv
                    unsigned u0 = __builtin_bit_cast(unsigned, v0);
                    unsigned u1 = __builtin_bit_cast(unsigned, v1);
                    bp0[0] += __builtin_bit_cast(h2, u0 << 16);
                    bp0[64] += __builtin_bit_cast(h2, u0 >> 16);
                    bp1[0] += __builtin_bit_cast(h2, u1 << 16);
                    bp1[64] += __builtin_bit_cast(h2, u1 >> 16);
                }
            }
        }
        // dense row k' = 4096 + lane
        ((_Float16*)mom)[w * RSH + 4096 + lane] = (_Float16)fmaxf(x[n * 64 + lane], 0.f);
    }

    // ---- GEMM: K-chunk for this wave (130 = 2*9 + 14*8)
    const int s0 = w * 8 + min(w, 2);
    const int s_end = s0 + 8 + (w < 2 ? 1 : 0);
    const int quad = lane >> 4;
    const _Float16* arow = (const _Float16*)mom + (lane & 15) * RSH;

    if (MODE == 3) {
        const uint4* Bp = (const uint4*)Wh;
        uint4 b0 = Bp[(size_t)(s0 + 0) * 64 + lane];  // prefetch before barrier
        uint4 b1 = Bp[(size_t)(s0 + 1) * 64 + lane];
        uint4 b2 = Bp[(size_t)(s0 + 2) * 64 + lane];
        uint4 b3 = Bp[(size_t)(s0 + 3) * 64 + lane];
        __syncthreads();
        f32x4 acc = {0, 0, 0, 0};
        for (int s = s0; s < s_end; ++s) {
            uint4 bq = b0;
            b0 = b1; b1 = b2; b2 = b3;
            if (s + 4 < s_end) b3 = Bp[(size_t)(s + 4) * 64 + lane];
            h8 a = *(const h8*)(arow + s * 32 + quad * 8);
            acc = __builtin_amdgcn_mfma_f32_16x16x32_f16(a, __builtin_bit_cast(h8, bq), acc,
                                                         0, 0, 0);
        }
        __syncthreads();
        f32x4* red = (f32x4*)mom;
        red[w * 64 + lane] = acc;
        __syncthreads();
        if (w == 0) {
            f32x4 s = {0, 0, 0, 0};
#pragma unroll
            for (int g = 0; g < 16; ++g) s += red[g * 64 + lane];
            const int co = lane & 15;
            if (co < 2) {
#pragma unroll
                for (int i = 0; i < 4; ++i) {
                    int nn = base + quad * 4 + i;
                    if (nn < nNodes) out[nn * 2 + co] = (s[i] + cb[co] + fb[co]) * (1.f / 128.f);
                }
            }
        }
    } else {
        const uint4* Bp = (const uint4*)Wh;
        uint4 b0[4], b1[4];
#pragma unroll
        for (int t = 0; t < 4; ++t) {  // prefetch before barrier
            b0[t] = Bp[((size_t)t * KSTEPS + s0) * 64 + lane];
            b1[t] = Bp[((size_t)t * KSTEPS + s0 + 1) * 64 + lane];
        }
        __syncthreads();
        f32x4 acc[4] = {{0, 0, 0, 0}, {0, 0, 0, 0}, {0, 0, 0, 0}, {0, 0, 0, 0}};
        for (int s = s0; s < s_end; ++s) {
            uint4 bq[4];
#pragma unroll
            for (int t = 0; t < 4; ++t) {
                bq[t] = b0[t];
                b0[t] = b1[t];
                if (s + 2 < s_end) b1[t] = Bp[((size_t)t * KSTEPS + s + 2) * 64 + lane];
            }
            h8 a = *(const h8*)(arow + s * 32 + quad * 8);
#pragma unroll
            for (int t = 0; t < 4; ++t)
                acc[t] = __builtin_amdgcn_mfma_f32_16x16x32_f16(
                    a, __builtin_bit_cast(h8, bq[t]), acc[t], 0, 0, 0);
        }
        __syncthreads();  // moments dead -> reuse as reduce scratch (64 KB)
        f32x4* red = (f32x4*)mom;
#pragma unroll
        for (int t = 0; t < 4; ++t) red[(w * 4 + t) * 64 + lane] = acc[t];
        __syncthreads();
        if (w < 4) {
            f32x4 s = {0, 0, 0, 0};
#pragma unroll
            for (int g = 0; g < 16; ++g) s += red[(g * 4 + w) * 64 + lane];
            const int co = w * 16 + (lane & 15);
#pragma unroll
            for (int i = 0; i < 4; ++i) {
                int nn = base + quad * 4 + i;
                if (nn < nNodes) {
                    float res = s[i] + cb[co] + fb[co];
                    if (MODE == 2) res += x[nn * 64 + co];
                    out[nn * 64 + co] = res;
                }
            }
        }
    }
}

// ---------------------------------------------------------------------------
// Layer 0 (CIN=4). TM=16, one wave per node: register-resident bin scatter
// (lane = 8x8 bin, moments in 4 VGPRs, all taps, no copies/reduce), then
// bf16 MFMA GEMM (waves 0,1) + dense lin branch (waves 2..9).
__global__ __launch_bounds__(1024, 4) void conv0_mfma(
    const float* __restrict__ x, const unsigned short* __restrict__ Wb,
    const float* __restrict__ cb, const float* __restrict__ fb, const float* __restrict__ fw,
    const int* __restrict__ offs, const int* __restrict__ csr_jk,
    const float4* __restrict__ csr_w4, float* __restrict__ out, int nNodes) {
    constexpr int TM = 16;
    constexpr int KSTEPS = 8;
    constexpr int RS = 256 + 12;    // 268
    extern __shared__ float mom[];  // [16][RS] = 17152 B
    const int tid = threadIdx.x;
    const int w = tid >> 6;
    const int lane = tid & 63;
    const int base = blockIdx.x * TM;
    const int n = base + w;

    {
        float4 z = make_float4(0.f, 0.f, 0.f, 0.f);
        float4* m4 = (float4*)mom;
        for (int i = tid; i < TM * RS / 4; i += 1024) m4[i] = z;
    }
    __syncthreads();

    if (n < nNodes) {
        const int e0 = offs[n], e1 = offs[n + 1];
        const int iu_l = lane >> 3, iv_l = lane & 7;
        f32x4 v = {0, 0, 0, 0};
        for (int e = e0; e < e1; ++e) {
            int jk = csr_jk[e];
            float4 w4 = csr_w4[e];
            int j = jk & 0x1FFFF;
            int r0 = ((jk >> 17) & 3) << 1;
            int r1 = (((jk >> 19) & 3) << 1) + 1;
            int iv = (jk >> 21) & 7;
            float wgt = 0.f;
            if (iu_l == r0) wgt = (iv_l == iv) ? w4.x : ((iv_l == iv + 1) ? w4.y : 0.f);
            else if (iu_l == r1) wgt = (iv_l == iv) ? w4.z : ((iv_l == iv + 1) ? w4.w : 0.f);
            const float4 xj = *(const float4*)(x + j * 4);
            v.x += wgt * xj.x;
            v.y += wgt * xj.y;
            v.z += wgt * xj.z;
            v.w += wgt * xj.w;
        }
        ((float4*)(mom + w * RS))[lane] = *(float4*)&v;
    }
    __syncthreads();

    const int quad = lane >> 4;
    const float* arow = mom + (lane & 15) * RS;
    if (w < 2) {
        const uint4* Bp = (const uint4*)Wb + (size_t)w * KSTEPS * 64;
        f32x4 acc = {0, 0, 0, 0};
        uint4 b0 = Bp[lane], b1 = Bp[64 + lane], b2 = Bp[128 + lane], b3 = Bp[192 + lane];
        for (int s = 0; s < KSTEPS; ++s) {
            uint4 bq = b0;
            b0 = b1; b1 = b2; b2 = b3;
            if (s + 4 < KSTEPS) b3 = Bp[(size_t)(s + 4) * 64 + lane];
            bf16x8 a = frag_from_lds_f32(arow, s, quad);
            acc = __builtin_amdgcn_mfma_f32_16x16x32_bf16(a, __builtin_bit_cast(bf16x8, bq),
                                                          acc, 0, 0, 0);
        }
        const int co = w * 16 + (lane & 15);
#pragma unroll
        for (int i = 0; i < 4; ++i) {
            int nn = base + quad * 4 + i;
            if (nn < nNodes) out[nn * 64 + 32 + co] = acc[i] + cb[co];
        }
    } else if (w < 10) {
        // dense lin branch -> cols 0..31 (no relu on layer-0 input)
        const int co = lane & 31;
        const int r = (w - 2) * 2 + (lane >> 5);
        int nn = base + r;
        if (nn < nNodes) {
            const float4 xr = *(const float4*)(x + nn * 4);
            float sdot = xr.x * fw[co] + xr.y * fw[32 + co] + xr.z * fw[64 + co] +
                         xr.w * fw[96 + co] + fb[co];
            out[nn * 64 + co] = sdot;
        }
    }
}

extern "C" void kernel_launch(void* const* d_in, const int* in_sizes, int n_in,
                              void* d_out, int out_size, void* d_ws, size_t ws_size,
                              hipStream_t stream) {
    const float* pos = (const float*)d_in[0];
    const float* feat = (const float*)d_in[1];
    const int* ei = (const int*)d_in[2];
    const int* ej = (const int*)d_in[3];
    const float* cw0 = (const float*)d_in[4];
    const float* cb0 = (const float*)d_in[5];
    const float* fw0 = (const float*)d_in[6];
    const float* fb0 = (const float*)d_in[7];
    const float* cw1 = (const float*)d_in[8];
    const float* cb1 = (const float*)d_in[9];
    const float* fw1 = (const float*)d_in[10];
    const float* fb1 = (const float*)d_in[11];
    const float* cw2 = (const float*)d_in[12];
    const float* cb2 = (const float*)d_in[13];
    const float* fw2 = (const float*)d_in[14];
    const float* fb2 = (const float*)d_in[15];
    const float* cw3 = (const float*)d_in[16];
    const float* cb3 = (const float*)d_in[17];
    const float* fw3 = (const float*)d_in[18];
    const float* fb3 = (const float*)d_in[19];
    float* outp = (float*)d_out;

    const int N = in_sizes[0] / 2;
    const int E = in_sizes[2];

    char* wsp = (char*)d_ws;
    size_t off = 0;
    auto alloc = [&](size_t bytes) -> void* {
        void* p = wsp + off;
        off = (off + bytes + 255) & ~(size_t)255;
        return p;
    };
    int* counts = (int*)alloc((size_t)N * 4);
    int* offs = (int*)alloc((size_t)(N + 1) * 4);
    int* cursor = (int*)alloc((size_t)N * 4);
    int* csr_jk = (int*)alloc((size_t)E * 4);
    float4* csr_w4 = (float4*)alloc((size_t)E * 16);
    uint2* csr_wh = (uint2*)alloc((size_t)E * 8);
    float* ansA = (float*)alloc((size_t)N * 64 * 4);
    float* ansB = (float*)alloc((size_t)N * 64 * 4);
    unsigned short* Wb0 = (unsigned short*)alloc((size_t)8192 * 2);
    _Float16* Wh1 = (_Float16*)alloc((size_t)4 * 130 * 512 * 2);
    _Float16* Wh2 = (_Float16*)alloc((size_t)4 * 130 * 512 * 2);
    _Float16* Wh3 = (_Float16*)alloc((size_t)1 * 130 * 512 * 2);
    (void)ws_size;
    (void)n_in;
    (void)out_size;

    const int BIG_LDS = 16 * 4168 * 2;          // 133376 B
    const int SMALL_LDS = 16 * (256 + 12) * 4;  // 17152 B
    hipFuncSetAttribute((const void*)&conv64_mfma<1>,
                        hipFuncAttributeMaxDynamicSharedMemorySize, BIG_LDS);
    hipFuncSetAttribute((const void*)&conv64_mfma<2>,
                        hipFuncAttributeMaxDynamicSharedMemorySize, BIG_LDS);
    hipFuncSetAttribute((const void*)&conv64_mfma<3>,
                        hipFuncAttributeMaxDynamicSharedMemorySize, BIG_LDS);

    zero_ints<<<dim3((N + 255) / 256), dim3(256), 0, stream>>>(counts, N);
    repack_wb0<<<dim3(32), dim3(256), 0, stream>>>(cw0, Wb0);
    repack_wh<<<dim3((4 * 130 * 512 + 255) / 256), dim3(256), 0, stream>>>(cw1, fw1, Wh1, 64, 4);
    repack_wh<<<dim3((4 * 130 * 512 + 255) / 256), dim3(256), 0, stream>>>(cw2, fw2, Wh2, 64, 4);
    repack_wh<<<dim3((1 * 130 * 512 + 255) / 256), dim3(256), 0, stream>>>(cw3, fw3, Wh3, 2, 1);
    edge_hist<<<dim3((E + 255) / 256), dim3(256), 0, stream>>>(ei, ej, counts, E);
    scan_kernel<<<dim3(1), dim3(1024), 0, stream>>>(counts, offs, cursor, N);
    edge_scatter<<<dim3((E + 255) / 256), dim3(256), 0, stream>>>(ei, ej, pos, cursor, csr_jk,
                                                                  csr_w4, csr_wh, E);

    const int nb = (N + 15) / 16;
    conv0_mfma<<<dim3(nb), dim3(1024), SMALL_LDS, stream>>>(
        feat, Wb0, cb0, fb0, fw0, offs, csr_jk, csr_w4, ansA, N);
    conv64_mfma<1><<<dim3(nb), dim3(1024), BIG_LDS, stream>>>(
        ansA, Wh1, cb1, fb1, offs, csr_jk, csr_wh, ansB, N);
    conv64_mfma<2><<<dim3(nb), dim3(1024), BIG_LDS, stream>>>(
        ansB, Wh2, cb2, fb2, offs, csr_jk, csr_wh, ansA, N);
    conv64_mfma<3><<<dim3(nb), dim3(1024), BIG_LDS, stream>>>(
        ansA, Wh3, cb3, fb3, offs, csr_jk, csr_wh, outp, N);
}

// Round 12
// 1143.375 us; speedup vs baseline: 3.1412x; 1.3013x over previous
//
#include <hip/hip_runtime.h>
#include <math.h>

typedef _Float16 h8 __attribute__((ext_vector_type(8)));
typedef _Float16 h2 __attribute__((ext_vector_type(2)));
typedef float f32x4 __attribute__((ext_vector_type(4)));

__device__ __forceinline__ float clampf(float x, float lo, float hi) {
    return fminf(fmaxf(x, lo), hi);
}

__global__ void zero_ints(int* __restrict__ p, int n) {
    int i = blockIdx.x * 256 + threadIdx.x;
    if (i < n) p[i] = 0;
}

// fp16 B-frag repack for CIN=64 layers, permuted k' layout:
// k' < 4096: rowi = k'>>9; ivd = (k'>>7)&3; c = (k'>>1)&63; slot = k'&1;
//            iv = ivd*2+slot; orig_k = (rowi*8+iv)*64 + c  -> cw
// k' >= 4096: fw row (k'-4096)
__global__ void repack_wh(const float* __restrict__ cw, const float* __restrict__ fw,
                          _Float16* __restrict__ Wh, int COUT, int COTILES) {
    int idx = blockIdx.x * 256 + threadIdx.x;
    int total = COTILES * 130 * 512;
    if (idx >= total) return;
    int j = idx & 7;
    int l = (idx >> 3) & 63;
    int rest = idx >> 9;
    int s = rest % 130;
    int t = rest / 130;
    int kp = s * 32 + (l >> 4) * 8 + j;
    int co = t * 16 + (l & 15);
    float v = 0.f;
    if (co < COUT) {
        if (kp < 4096) {
            int rowi = kp >> 9;
            int ivd = (kp >> 7) & 3;
            int c = (kp >> 1) & 63;
            int slot = kp & 1;
            int iv = ivd * 2 + slot;
            v = cw[((rowi * 8 + iv) * 64 + c) * COUT + co];
        } else {
            v = fw[(kp - 4096) * COUT + co];
        }
    }
    Wh[idx] = (_Float16)v;
}

__global__ void edge_hist(const int* __restrict__ ei, const int* __restrict__ ej,
                          int* __restrict__ counts, int E) {
    int e = blockIdx.x * 256 + threadIdx.x;
    if (e >= E) return;
    int i = ei[e], j = ej[e];
    if (i != j) atomicAdd(&counts[i], 1);
}

__global__ __launch_bounds__(1024) void scan_kernel(const int* __restrict__ counts,
                                                    int* __restrict__ offs,
                                                    int* __restrict__ cursor, int N) {
    __shared__ int sums[1024];
    const int t = threadIdx.x;
    const int per = (N + 1023) / 1024;
    const int lo = t * per;
    const int hi = min(lo + per, N);
    int s = 0;
    for (int i = lo; i < hi; ++i) s += counts[i];
    sums[t] = s;
    __syncthreads();
    for (int d = 1; d < 1024; d <<= 1) {
        int v = (t >= d) ? sums[t - d] : 0;
        __syncthreads();
        sums[t] += v;
        __syncthreads();
    }
    int run = (t > 0) ? sums[t - 1] : 0;
    for (int i = lo; i < hi; ++i) {
        offs[i] = run;
        cursor[i] = run;
        run += counts[i];
    }
    if (t == 1023) offs[N] = sums[1023];
}

// csr_all[e] = uint4:
//   .x = j[0:17) | r0>>1 [17:19) | r1>>1 [19:21) | iv [21:24)
//   .y = o0[0:11) | o1[11:22) | odd[22]   (o0/o1 = r*256+ivd*64, h2 units)
//   .z = fp16x2 {wu0*gv, wu0*fv}   (even u-row r0)
//   .w = fp16x2 {wu1*gv, wu1*fv}   (odd  u-row r1)
__global__ void edge_scatter(const int* __restrict__ ei, const int* __restrict__ ej,
                             const float* __restrict__ pos, int* __restrict__ cursor,
                             uint4* __restrict__ csr_all, int E) {
    int e = blockIdx.x * 256 + threadIdx.x;
    if (e >= E) return;
    int i = ei[e], j = ej[e];
    if (i == j) return;
    float dx = clampf(pos[i * 2 + 0] - pos[j * 2 + 0], -1.f, 1.f);
    float dy = clampf(pos[i * 2 + 1] - pos[j * 2 + 1], -1.f, 1.f);
    float r = sqrtf(dx * dx + dy * dy + 1e-12f);
    float u = clampf(2.f * r - 1.f, -1.f, 1.f);
    float v = atan2f(dy, dx) * 0.3183098861837907f;  // / pi
    float tu = (u + 1.f) * 3.5f;
    float tv = (v + 1.f) * 3.5f;
    int iu = min(6, max(0, (int)floorf(tu)));
    int iv = min(6, max(0, (int)floorf(tv)));
    float fu = clampf(tu - (float)iu, 0.f, 1.f);
    float fv = clampf(tv - (float)iv, 0.f, 1.f);
    bool even = (iu & 1) == 0;
    int rowi0 = even ? iu : iu + 1;  // even u-row
    int rowi1 = even ? iu + 1 : iu;  // odd u-row
    float wu0 = even ? (1.f - fu) : fu;
    float wu1 = even ? fu : (1.f - fu);
    float gv = 1.f - fv;
    int ivd = iv >> 1;
    unsigned o0 = (unsigned)(rowi0 * 256 + ivd * 64);
    unsigned o1 = (unsigned)(rowi1 * 256 + ivd * 64);
    unsigned offp = o0 | (o1 << 11) | ((unsigned)(iv & 1) << 22);
    unsigned a0 = (unsigned)__builtin_bit_cast(unsigned short, (_Float16)(wu0 * gv)) |
                  ((unsigned)__builtin_bit_cast(unsigned short, (_Float16)(wu0 * fv)) << 16);
    unsigned a1 = (unsigned)__builtin_bit_cast(unsigned short, (_Float16)(wu1 * gv)) |
                  ((unsigned)__builtin_bit_cast(unsigned short, (_Float16)(wu1 * fv)) << 16);
    int p = atomicAdd(&cursor[i], 1);
    csr_all[p] = make_uint4(
        (unsigned)j | ((unsigned)(rowi0 >> 1) << 17) | ((unsigned)(rowi1 >> 1) << 19) |
            ((unsigned)iv << 21),
        offp, a0, a1);
}

// ---------------------------------------------------------------------------
// Layers 1..2 (CIN=64, COUT=64). 1024 threads = 16 waves = 16 nodes, fp16
// moments, one wave per node applying all 4 taps (race-free: lane=channel,
// same-lane RMWs program-ordered). Prebaked h2 offsets from csr_all.y.
// Plain RMW (no ds atomics: 3x slower, round 6). 133 KB LDS, 1 block/CU.
// GEMM: 16-way K-split, direct fp16 A-frags, f16 MFMA, partial-reduce in LDS.
// MODE 1: relu in, out = conv(+dense row) + cb + fb ; MODE 2: + residual x
template <int MODE>
__global__ __launch_bounds__(1024, 4) void conv64_mfma(
    const float* __restrict__ x, const _Float16* __restrict__ Wh,
    const float* __restrict__ cb, const float* __restrict__ fb,
    const int* __restrict__ offs, const uint4* __restrict__ csr_all,
    float* __restrict__ out, int nNodes) {
    constexpr int TM = 16;
    constexpr int KSTEPS = 130;
    constexpr int RSH = 4168;       // halfs per node row (8336 B)
    constexpr int RSD = RSH / 2;    // h2 per row
    extern __shared__ float mom[];  // 16 * 8336 B = 133376 B
    const int tid = threadIdx.x;
    const int w = tid >> 6;
    const int lane = tid & 63;
    const int base = blockIdx.x * TM;
    const int n = base + w;

    {  // zero moments
        float4 z = make_float4(0.f, 0.f, 0.f, 0.f);
        float4* m4 = (float4*)mom;
        for (int i = tid; i < TM * RSH / 8; i += 1024) m4[i] = z;
    }
    __syncthreads();

    // ---- scatter
    if (n < nNodes) {
        const int e0 = offs[n], e1 = offs[n + 1];
        h2* momn2 = (h2*)mom + w * RSD;
        const int c = lane;
        for (int b = e0; b < e1; b += 4) {
            uint4 ca[4];
            float xv[4];
#pragma unroll
            for (int u = 0; u < 4; ++u) {
                int e = b + u;
                bool ok = e < e1;
                ca[u] = csr_all[ok ? e : e0];
                xv[u] = ok ? 1.f : 0.f;
            }
#pragma unroll
            for (int u = 0; u < 4; ++u) {
                int j = ca[u].x & 0x1FFFF;
                xv[u] *= fmaxf(x[j * 64 + c], 0.f);
            }
#pragma unroll
            for (int u = 0; u < 4; ++u) {
                int o0 = ca[u].y & 0x7FF;
                int o1 = (ca[u].y >> 11) & 0x7FF;
                _Float16 xh = (_Float16)xv[u];
                h2 xh2 = {xh, xh};
                h2 v0 = xh2 * __builtin_bit_cast(h2, ca[u].z);
                h2 v1 = xh2 * __builtin_bit_cast(h2, ca[u].w);
                h2* bp0 = momn2 + o0 + c;
                h2* bp1 = momn2 + o1 + c;
                if (!(ca[u].y >> 22)) {  // wave-uniform branch
                    bp0[0] += v0;
                    bp1[0] += v1;
                } else {
                    unsigned u0 = __builtin_bit_cast(unsigned, v0);
                    unsigned u1 = __builtin_bit_cast(unsigned, v1);
                    bp0[0] += __builtin_bit_cast(h2, u0 << 16);
                    bp0[64] += __builtin_bit_cast(h2, u0 >> 16);
                    bp1[0] += __builtin_bit_cast(h2, u1 << 16);
                    bp1[64] += __builtin_bit_cast(h2, u1 >> 16);
                }
            }
        }
        // dense row k' = 4096 + lane
        ((_Float16*)mom)[w * RSH + 4096 + lane] = (_Float16)fmaxf(x[n * 64 + lane], 0.f);
    }

    // ---- GEMM: K-chunk for this wave (130 = 2*9 + 14*8)
    const int s0 = w * 8 + min(w, 2);
    const int s_end = s0 + 8 + (w < 2 ? 1 : 0);
    const int quad = lane >> 4;
    const _Float16* arow = (const _Float16*)mom + (lane & 15) * RSH;

    const uint4* Bp = (const uint4*)Wh;
    uint4 b0[4], b1[4];
#pragma unroll
    for (int t = 0; t < 4; ++t) {  // prefetch before barrier
        b0[t] = Bp[((size_t)t * KSTEPS + s0) * 64 + lane];
        b1[t] = Bp[((size_t)t * KSTEPS + s0 + 1) * 64 + lane];
    }
    __syncthreads();
    f32x4 acc[4] = {{0, 0, 0, 0}, {0, 0, 0, 0}, {0, 0, 0, 0}, {0, 0, 0, 0}};
    for (int s = s0; s < s_end; ++s) {
        uint4 bq[4];
#pragma unroll
        for (int t = 0; t < 4; ++t) {
            bq[t] = b0[t];
            b0[t] = b1[t];
            if (s + 2 < s_end) b1[t] = Bp[((size_t)t * KSTEPS + s + 2) * 64 + lane];
        }
        h8 a = *(const h8*)(arow + s * 32 + quad * 8);
#pragma unroll
        for (int t = 0; t < 4; ++t)
            acc[t] = __builtin_amdgcn_mfma_f32_16x16x32_f16(a, __builtin_bit_cast(h8, bq[t]),
                                                            acc[t], 0, 0, 0);
    }
    __syncthreads();  // moments dead -> reuse as reduce scratch
    f32x4* red = (f32x4*)mom;
#pragma unroll
    for (int t = 0; t < 4; ++t) red[(w * 4 + t) * 64 + lane] = acc[t];
    __syncthreads();
    if (w < 4) {
        f32x4 s = {0, 0, 0, 0};
#pragma unroll
        for (int g = 0; g < 16; ++g) s += red[(g * 4 + w) * 64 + lane];
        const int co = w * 16 + (lane & 15);
#pragma unroll
        for (int i = 0; i < 4; ++i) {
            int nn = base + quad * 4 + i;
            if (nn < nNodes) {
                float res = s[i] + cb[co] + fb[co];
                if (MODE == 2) res += x[nn * 64 + co];
                out[nn * 64 + co] = res;
            }
        }
    }
}

// ---------------------------------------------------------------------------
// Layer 3 (CIN=64, COUT=2): direct per-edge form, no moments/GEMM.
// out[n,co] = (sum_e sum_tap w_tap * relu(x[j])^T W3[bin,:,co]
//              + relu(x[n])^T fw3 + cb3 + fb3) / 128
// W3 = raw cw3 [4096][2] staged to LDS as float2 (32 KB); fw3 float2[64].
// One wave per node, lane = channel, fp32 register accumulation (no RMW).
__global__ __launch_bounds__(1024, 4) void conv_last(
    const float* __restrict__ x, const float* __restrict__ cw3, const float* __restrict__ fw3,
    const float* __restrict__ cb3, const float* __restrict__ fb3,
    const int* __restrict__ offs, const uint4* __restrict__ csr_all,
    float* __restrict__ out, int nNodes) {
    constexpr int TM = 16;
    __shared__ float2 W2[4096];   // 32 KB
    __shared__ float2 FW2[64];    // 512 B
    const int tid = threadIdx.x;
    const int w = tid >> 6;
    const int lane = tid & 63;
    const int base = blockIdx.x * TM;
    const int n = base + w;

    {  // stage weights
        const float2* src = (const float2*)cw3;
        for (int d = tid; d < 4096; d += 1024) W2[d] = src[d];
        if (tid < 64) FW2[tid] = ((const float2*)fw3)[tid];
    }
    __syncthreads();

    float2 acc = make_float2(0.f, 0.f);
    if (n < nNodes) {
        const int e0 = offs[n], e1 = offs[n + 1];
        const int c = lane;
        for (int b = e0; b < e1; b += 4) {
            uint4 ca[4];
            float xv[4];
#pragma unroll
            for (int u = 0; u < 4; ++u) {
                int e = b + u;
                bool ok = e < e1;
                ca[u] = csr_all[ok ? e : e0];
                xv[u] = ok ? 1.f : 0.f;
            }
#pragma unroll
            for (int u = 0; u < 4; ++u) {
                int j = ca[u].x & 0x1FFFF;
                xv[u] *= fmaxf(x[j * 64 + c], 0.f);
            }
#pragma unroll
            for (int u = 0; u < 4; ++u) {
                int r0 = ((ca[u].x >> 17) & 3) << 1;
                int r1 = (((ca[u].x >> 19) & 3) << 1) + 1;
                int iv = (ca[u].x >> 21) & 7;
                h2 wh0 = __builtin_bit_cast(h2, ca[u].z);
                h2 wh1 = __builtin_bit_cast(h2, ca[u].w);
                float w00 = (float)wh0[0], w01 = (float)wh0[1];
                float w10 = (float)wh1[0], w11 = (float)wh1[1];
                int b00 = (r0 * 8 + iv) * 64 + c;
                int b10 = (r1 * 8 + iv) * 64 + c;
                float2 t00 = W2[b00], t01 = W2[b00 + 64];
                float2 t10 = W2[b10], t11 = W2[b10 + 64];
                float wsx = w00 * t00.x + w01 * t01.x + w10 * t10.x + w11 * t11.x;
                float wsy = w00 * t00.y + w01 * t01.y + w10 * t10.y + w11 * t11.y;
                acc.x += xv[u] * wsx;
                acc.y += xv[u] * wsy;
            }
        }
        // dense branch
        float xr = fmaxf(x[n * 64 + c], 0.f);
        float2 fwp = FW2[c];
        acc.x += xr * fwp.x;
        acc.y += xr * fwp.y;
    }
    // butterfly reduce over 64 lanes
#pragma unroll
    for (int d = 1; d < 64; d <<= 1) {
        acc.x += __shfl_xor(acc.x, d);
        acc.y += __shfl_xor(acc.y, d);
    }
    if (lane == 0 && n < nNodes) {
        out[n * 2 + 0] = (acc.x + cb3[0] + fb3[0]) * (1.f / 128.f);
        out[n * 2 + 1] = (acc.y + cb3[1] + fb3[1]) * (1.f / 128.f);
    }
}

// ---------------------------------------------------------------------------
// Layer 0 (CIN=4, no relu on input): direct per-edge form.
// lane = (co 0..31, chalf h). conv: acc = sum_e sum_tap w * (x_{2h} W0[bin,2h,co]
// + x_{2h+1} W0[bin,2h+1,co]); lin: x[n]^T fw0. Pair-reduce (lane ^ 32), write
// [lin | conv]. W0p LDS layout [bin][h][co] float2(c=2h, 2h+1) = 32 KB.
__global__ __launch_bounds__(1024, 4) void conv0_direct(
    const float* __restrict__ x, const float* __restrict__ cw0, const float* __restrict__ fw0,
    const float* __restrict__ cb0, const float* __restrict__ fb0,
    const int* __restrict__ offs, const uint4* __restrict__ csr_all,
    float* __restrict__ out, int nNodes) {
    constexpr int TM = 16;
    __shared__ float2 W0p[4096];  // 32 KB
    __shared__ float2 FW0p[64];   // [h*32+co] = (fw0[2h][co], fw0[2h+1][co])
    const int tid = threadIdx.x;
    const int w = tid >> 6;
    const int lane = tid & 63;
    const int base = blockIdx.x * TM;
    const int n = base + w;

    {  // stage W0 permuted
        for (int d = tid; d < 4096; d += 1024) {
            int co = d & 31;
            int h = (d >> 5) & 1;
            int bin = d >> 6;
            W0p[d] = make_float2(cw0[(bin * 4 + 2 * h) * 32 + co],
                                 cw0[(bin * 4 + 2 * h + 1) * 32 + co]);
        }
        if (tid < 64) {
            int co = tid & 31;
            int h = tid >> 5;
            FW0p[tid] = make_float2(fw0[(2 * h) * 32 + co], fw0[(2 * h + 1) * 32 + co]);
        }
    }
    __syncthreads();

    const int co = lane & 31;
    const int h = lane >> 5;
    float accC = 0.f, accL = 0.f;
    if (n < nNodes) {
        const int e0 = offs[n], e1 = offs[n + 1];
        for (int b = e0; b < e1; b += 4) {
            uint4 ca[4];
            float xc0[4], xc1[4];
#pragma unroll
            for (int u = 0; u < 4; ++u) {
                int e = b + u;
                bool ok = e < e1;
                ca[u] = csr_all[ok ? e : e0];
                xc0[u] = ok ? 1.f : 0.f;
            }
#pragma unroll
            for (int u = 0; u < 4; ++u) {
                int j = ca[u].x & 0x1FFFF;
                const float4 xj = *(const float4*)(x + j * 4);  // no relu (layer 0)
                float a = h ? xj.z : xj.x;
                float bb = h ? xj.w : xj.y;
                xc1[u] = xc0[u] * bb;
                xc0[u] = xc0[u] * a;
            }
#pragma unroll
            for (int u = 0; u < 4; ++u) {
                int r0 = ((ca[u].x >> 17) & 3) << 1;
                int r1 = (((ca[u].x >> 19) & 3) << 1) + 1;
                int iv = (ca[u].x >> 21) & 7;
                h2 wh0 = __builtin_bit_cast(h2, ca[u].z);
                h2 wh1 = __builtin_bit_cast(h2, ca[u].w);
                float w00 = (float)wh0[0], w01 = (float)wh0[1];
                float w10 = (float)wh1[0], w11 = (float)wh1[1];
                int i00 = ((r0 * 8 + iv) * 2 + h) * 32 + co;
                int i10 = ((r1 * 8 + iv) * 2 + h) * 32 + co;
                float2 t00 = W0p[i00], t01 = W0p[i00 + 64];
                float2 t10 = W0p[i10], t11 = W0p[i10 + 64];
                accC += w00 * (xc0[u] * t00.x + xc1[u] * t00.y);
                accC += w01 * (xc0[u] * t01.x + xc1[u] * t01.y);
                accC += w10 * (xc0[u] * t10.x + xc1[u] * t10.y);
                accC += w11 * (xc0[u] * t11.x + xc1[u] * t11.y);
            }
        }
        // lin branch (no relu)
        const float4 xn = *(const float4*)(x + n * 4);
        float a = h ? xn.z : xn.x;
        float bb = h ? xn.w : xn.y;
        float2 fwp = FW0p[h * 32 + co];
        accL = a * fwp.x + bb * fwp.y;
    }
    accC += __shfl_xor(accC, 32);
    accL += __shfl_xor(accL, 32);
    if (lane < 32 && n < nNodes) {
        out[n * 64 + co] = accL + fb0[co];
        out[n * 64 + 32 + co] = accC + cb0[co];
    }
}

extern "C" void kernel_launch(void* const* d_in, const int* in_sizes, int n_in,
                              void* d_out, int out_size, void* d_ws, size_t ws_size,
                              hipStream_t stream) {
    const float* pos = (const float*)d_in[0];
    const float* feat = (const float*)d_in[1];
    const int* ei = (const int*)d_in[2];
    const int* ej = (const int*)d_in[3];
    const float* cw0 = (const float*)d_in[4];
    const float* cb0 = (const float*)d_in[5];
    const float* fw0 = (const float*)d_in[6];
    const float* fb0 = (const float*)d_in[7];
    const float* cw1 = (const float*)d_in[8];
    const float* cb1 = (const float*)d_in[9];
    const float* fw1 = (const float*)d_in[10];
    const float* fb1 = (const float*)d_in[11];
    const float* cw2 = (const float*)d_in[12];
    const float* cb2 = (const float*)d_in[13];
    const float* fw2 = (const float*)d_in[14];
    const float* fb2 = (const float*)d_in[15];
    const float* cw3 = (const float*)d_in[16];
    const float* cb3 = (const float*)d_in[17];
    const float* fw3 = (const float*)d_in[18];
    const float* fb3 = (const float*)d_in[19];
    float* outp = (float*)d_out;

    const int N = in_sizes[0] / 2;
    const int E = in_sizes[2];

    char* wsp = (char*)d_ws;
    size_t off = 0;
    auto alloc = [&](size_t bytes) -> void* {
        void* p = wsp + off;
        off = (off + bytes + 255) & ~(size_t)255;
        return p;
    };
    int* counts = (int*)alloc((size_t)N * 4);
    int* offs = (int*)alloc((size_t)(N + 1) * 4);
    int* cursor = (int*)alloc((size_t)N * 4);
    uint4* csr_all = (uint4*)alloc((size_t)E * 16);
    float* ansA = (float*)alloc((size_t)N * 64 * 4);
    float* ansB = (float*)alloc((size_t)N * 64 * 4);
    _Float16* Wh1 = (_Float16*)alloc((size_t)4 * 130 * 512 * 2);
    _Float16* Wh2 = (_Float16*)alloc((size_t)4 * 130 * 512 * 2);
    (void)ws_size;
    (void)n_in;
    (void)out_size;

    const int BIG_LDS = 16 * 4168 * 2;  // 133376 B
    hipFuncSetAttribute((const void*)&conv64_mfma<1>,
                        hipFuncAttributeMaxDynamicSharedMemorySize, BIG_LDS);
    hipFuncSetAttribute((const void*)&conv64_mfma<2>,
                        hipFuncAttributeMaxDynamicSharedMemorySize, BIG_LDS);

    zero_ints<<<dim3((N + 255) / 256), dim3(256), 0, stream>>>(counts, N);
    repack_wh<<<dim3((4 * 130 * 512 + 255) / 256), dim3(256), 0, stream>>>(cw1, fw1, Wh1, 64, 4);
    repack_wh<<<dim3((4 * 130 * 512 + 255) / 256), dim3(256), 0, stream>>>(cw2, fw2, Wh2, 64, 4);
    edge_hist<<<dim3((E + 255) / 256), dim3(256), 0, stream>>>(ei, ej, counts, E);
    scan_kernel<<<dim3(1), dim3(1024), 0, stream>>>(counts, offs, cursor, N);
    edge_scatter<<<dim3((E + 255) / 256), dim3(256), 0, stream>>>(ei, ej, pos, cursor, csr_all, E);

    const int nb = (N + 15) / 16;
    conv0_direct<<<dim3(nb), dim3(1024), 0, stream>>>(
        feat, cw0, fw0, cb0, fb0, offs, csr_all, ansA, N);
    conv64_mfma<1><<<dim3(nb), dim3(1024), BIG_LDS, stream>>>(
        ansA, Wh1, cb1, fb1, offs, csr_all, ansB, N);
    conv64_mfma<2><<<dim3(nb), dim3(1024), BIG_LDS, stream>>>(
        ansB, Wh2, cb2, fb2, offs, csr_all, ansA, N);
    conv_last<<<dim3(nb), dim3(1024), 0, stream>>>(
        ansA, cw3, fw3, cb3, fb3, offs, csr_all, outp, N);
}